// Round 1
// 1251.676 us; speedup vs baseline: 1.1442x; 1.1442x over previous
//
#include <hip/hip_runtime.h>
#include <hip/hip_bf16.h>
#include <stdint.h>

#define TOKENS 8192
#define OUTF   11008
#define INF    4096
#define NCODES (45088768)   // OUTF * INF

typedef __bf16 bf16x8 __attribute__((ext_vector_type(8)));
typedef float  f32x4  __attribute__((ext_vector_type(4)));

__device__ __forceinline__ unsigned short f32_to_bf16_rne(float f) {
    union { float f; unsigned int u; } v; v.f = f;
    unsigned int u = v.u;
    unsigned int r = u + 0x7fffu + ((u >> 16) & 1u);
    return (unsigned short)(r >> 16);
}

// ---------------- dequant W: codes(int32) * codebook * absmax -> bf16 ----------------
__global__ __launch_bounds__(256) void dequant_w(const int* __restrict__ codes,
                                                 const float* __restrict__ absmax,
                                                 const float* __restrict__ codebook,
                                                 unsigned short* __restrict__ wq) {
    __shared__ float cb[16];
    if (threadIdx.x < 16) cb[threadIdx.x] = codebook[threadIdx.x];
    __syncthreads();
    size_t idx = ((size_t)blockIdx.x * 256 + threadIdx.x) * 8;   // grid sized exactly
    float am = absmax[idx >> 6];                                  // 8 | 64 -> one absmax per 8-chunk
    const int4* cp = (const int4*)(codes + idx);
    int4 c0 = cp[0];
    int4 c1 = cp[1];
    union { unsigned short s[8]; uint4 v; } u;
    u.s[0] = f32_to_bf16_rne(cb[c0.x] * am);
    u.s[1] = f32_to_bf16_rne(cb[c0.y] * am);
    u.s[2] = f32_to_bf16_rne(cb[c0.z] * am);
    u.s[3] = f32_to_bf16_rne(cb[c0.w] * am);
    u.s[4] = f32_to_bf16_rne(cb[c1.x] * am);
    u.s[5] = f32_to_bf16_rne(cb[c1.y] * am);
    u.s[6] = f32_to_bf16_rne(cb[c1.z] * am);
    u.s[7] = f32_to_bf16_rne(cb[c1.w] * am);
    *(uint4*)(wq + idx) = u.v;
}

// ---------------- cast x: fp32 -> bf16 ----------------
__global__ __launch_bounds__(256) void cast_x(const float* __restrict__ x,
                                              unsigned short* __restrict__ xq) {
    size_t idx = ((size_t)blockIdx.x * 256 + threadIdx.x) * 8;   // grid sized exactly
    float4 a = *(const float4*)(x + idx);
    float4 b = *(const float4*)(x + idx + 4);
    union { unsigned short s[8]; uint4 v; } u;
    u.s[0] = f32_to_bf16_rne(a.x);
    u.s[1] = f32_to_bf16_rne(a.y);
    u.s[2] = f32_to_bf16_rne(a.z);
    u.s[3] = f32_to_bf16_rne(a.w);
    u.s[4] = f32_to_bf16_rne(b.x);
    u.s[5] = f32_to_bf16_rne(b.y);
    u.s[6] = f32_to_bf16_rne(b.z);
    u.s[7] = f32_to_bf16_rne(b.w);
    *(uint4*)(xq + idx) = u.v;
}

// ======================= 256x256 8-phase bf16 MFMA GEMM (m201 template port) =======================
// C[M,N] = X[M,K] * W[N,K]^T + bias.  BM=BN=256, BK=64, 512 thr (2x4 waves), LDS 128KiB dbuf.
// Per-wave output 128x64, arranged so compute-quadrant (mh,nh) == staging half:
//   A rows: mh*128 + wm_l*64 + i*16 + frow       B rows: nh*128 + wn_l*32 + j*16 + frow
// Staging order per K-tile [A0,B1,A1,B0] == last-read order +1 phase (slot-overwrite safe by
// one barrier epoch).  vmcnt(6) at phases 4/8 only: 3 half-tiles (6 loads) stay in flight.
// LDS swizzle: 16B-granule XOR g^=(row&7) — linear LDS dest, inverse-swizzled global source
// for global_load_lds, swizzled ds_read (both-sides involution, rule #21).
#define BM 256
#define BN 256
#define BK 64

#define GLLDS(SRC, DST)                                                                   \
    __builtin_amdgcn_global_load_lds((const __attribute__((address_space(1))) void*)(SRC),\
                                     (__attribute__((address_space(3))) void*)(DST), 16, 0, 0)

#define STAGE_A(KT, HALF, BUF) do {                                                       \
    const unsigned short* _s = gA + (size_t)(HALF) * (128 * INF) + (size_t)(KT) * BK;     \
    GLLDS(_s,                   &lA[BUF][(HALF) * 8192 + tid * 8]);                       \
    GLLDS(_s + (size_t)64 * INF, &lA[BUF][(HALF) * 8192 + tid * 8 + 4096]); } while (0)

#define STAGE_B(KT, HALF, BUF) do {                                                       \
    const unsigned short* _s = gB + (size_t)(HALF) * (128 * INF) + (size_t)(KT) * BK;     \
    GLLDS(_s,                   &lB[BUF][(HALF) * 8192 + tid * 8]);                       \
    GLLDS(_s + (size_t)64 * INF, &lB[BUF][(HALF) * 8192 + tid * 8 + 4096]); } while (0)

#define LOAD_A(BUF, MH) do { _Pragma("unroll")                                            \
    for (int i = 0; i < 4; ++i) {                                                         \
        a[i][0] = *(const bf16x8*)&lA[BUF][(MH) * 8192 + i * 1024 + aRow + sw0];          \
        a[i][1] = *(const bf16x8*)&lA[BUF][(MH) * 8192 + i * 1024 + aRow + sw1]; } } while (0)

#define LOAD_B(BUF, NH) do { _Pragma("unroll")                                            \
    for (int j = 0; j < 2; ++j) {                                                         \
        b[j][0] = *(const bf16x8*)&lB[BUF][(NH) * 8192 + j * 1024 + bRow + sw0];          \
        b[j][1] = *(const bf16x8*)&lB[BUF][(NH) * 8192 + j * 1024 + bRow + sw1]; } } while (0)

#define MFMA_Q(MH, NH) do {                                                               \
    __builtin_amdgcn_s_setprio(1);                                                        \
    _Pragma("unroll") for (int kc = 0; kc < 2; ++kc)                                      \
    _Pragma("unroll") for (int i = 0; i < 4; ++i)                                         \
    _Pragma("unroll") for (int j = 0; j < 2; ++j)                                         \
        acc[MH][i][NH][j] = __builtin_amdgcn_mfma_f32_16x16x32_bf16(                      \
            a[i][kc], b[j][kc], acc[MH][i][NH][j], 0, 0, 0);                              \
    __builtin_amdgcn_s_setprio(0); } while (0)

#define BARR   __builtin_amdgcn_s_barrier()
#define LGKM0  asm volatile("s_waitcnt lgkmcnt(0)" ::: "memory")
#define VMC(N) asm volatile("s_waitcnt vmcnt(" #N ")" ::: "memory")

__global__ __launch_bounds__(512, 2) void gemm_bf16_8p(const unsigned short* __restrict__ Xb,  // [TOKENS][INF]
                                                       const unsigned short* __restrict__ Wb,  // [OUTF][INF]
                                                       const float* __restrict__ bias,
                                                       float* __restrict__ out) {
    __shared__ __align__(16) unsigned short lA[2][BM * BK];   // 2 x 32KB
    __shared__ __align__(16) unsigned short lB[2][BN * BK];   // 2 x 32KB

    // grid: 32 m-tiles x 43 n-tiles = 1376 = 8*172 -> bijective chunked XCD swizzle (T1).
    // Each XCD owns a 4m x 43n region; iterate m-minor so the ~32 concurrent blocks/XCD
    // share a 4x256-row X k-slice (128KB) + 8x256-row W k-slice (256KB) in its 4MB L2.
    const int bid  = blockIdx.x;
    const int xcd  = bid & 7;
    const int loc  = bid >> 3;          // 0..171
    const int mt   = xcd * 4 + (loc & 3);
    const int nt   = loc >> 2;          // 0..42
    const int m0   = mt * BM;
    const int n0   = nt * BN;

    const int tid  = threadIdx.x;
    const int lane = tid & 63;
    const int wave = tid >> 6;          // 0..7
    const int wm_l = wave >> 2;         // 0..1
    const int wn_l = wave & 3;          // 0..3

    // fragment-read addressing (swizzled): row&7 == lane&7 for every frag row
    const int frow = lane & 15;
    const int klan = lane >> 4;                  // 0..3
    const int f7   = lane & 7;
    const int sw0  = ((klan)     ^ f7) * 8;      // kc=0 granule offset (elems)
    const int sw1  = ((klan + 4) ^ f7) * 8;      // kc=1
    const int aRow = (wm_l * 64 + frow) * BK;
    const int bRow = (wn_l * 32 + frow) * BK;

    // staging: chunk tid = (row rl, granule tid&7); source pre-swizzled by g^(rl&7)
    const int rl   = tid >> 3;                   // 0..63
    const int gsw  = (tid & 7) ^ (rl & 7);
    const unsigned short* gA = Xb + (size_t)(m0 + rl) * INF + gsw * 8;
    const unsigned short* gB = Wb + (size_t)(n0 + rl) * INF + gsw * 8;

    f32x4 acc[2][4][2][2];
#pragma unroll
    for (int mh = 0; mh < 2; ++mh)
#pragma unroll
        for (int i = 0; i < 4; ++i)
#pragma unroll
            for (int nh = 0; nh < 2; ++nh)
#pragma unroll
                for (int j = 0; j < 2; ++j)
#pragma unroll
                    for (int r = 0; r < 4; ++r) acc[mh][i][nh][j][r] = 0.0f;

    bf16x8 a[4][2], b[2][2];

    // -------- prologue: stage h0..h6 (Kt0 full + Kt1 A0,B1,A1), land Kt0 --------
    STAGE_A(0, 0, 0); STAGE_B(0, 1, 0); STAGE_A(0, 1, 0); STAGE_B(0, 0, 0);
    STAGE_A(1, 0, 1); STAGE_B(1, 1, 1); STAGE_A(1, 1, 1);
    VMC(6);
    BARR;

    // -------- main loop: 31 iters x 2 K-tiles; 8 phases/iter --------
    for (int it = 0; it < 31; ++it) {
        const int kt1 = 2 * it + 1, kt2 = 2 * it + 2, kt3 = 2 * it + 3;
        // ph1: q(0,0) of Kt(2it) in buf0
        LOAD_A(0, 0); LOAD_B(0, 0); STAGE_B(kt1, 0, 1);
        BARR; LGKM0; MFMA_Q(0, 0); BARR;
        // ph2: q(0,1)
        LOAD_B(0, 1); STAGE_A(kt2, 0, 0);
        BARR; LGKM0; MFMA_Q(0, 1); BARR;
        // ph3: q(1,1)
        LOAD_A(0, 1); STAGE_B(kt2, 1, 0);
        BARR; LGKM0; MFMA_Q(1, 1); BARR;
        // ph4: q(1,0); counted drain -> Kt(2it+1) fully landed
        LOAD_B(0, 0); STAGE_A(kt2, 1, 0);
        BARR; LGKM0; MFMA_Q(1, 0); VMC(6); BARR;
        // ph5: q(0,0) of Kt(2it+1) in buf1
        LOAD_A(1, 0); LOAD_B(1, 0); STAGE_B(kt2, 0, 0);
        BARR; LGKM0; MFMA_Q(0, 0); BARR;
        // ph6: q(0,1)
        LOAD_B(1, 1); STAGE_A(kt3, 0, 1);
        BARR; LGKM0; MFMA_Q(0, 1); BARR;
        // ph7: q(1,1)
        LOAD_A(1, 1); STAGE_B(kt3, 1, 1);
        BARR; LGKM0; MFMA_Q(1, 1); BARR;
        // ph8: q(1,0); counted drain -> Kt(2it+2) fully landed
        LOAD_B(1, 0); STAGE_A(kt3, 1, 1);
        BARR; LGKM0; MFMA_Q(1, 0); VMC(6); BARR;
    }

    // -------- epilogue: Kt62 (buf0) + Kt63 (buf1); stage only h255, drain once --------
    LOAD_A(0, 0); LOAD_B(0, 0); STAGE_B(63, 0, 1);
    BARR; LGKM0; MFMA_Q(0, 0); BARR;
    LOAD_B(0, 1);
    BARR; LGKM0; MFMA_Q(0, 1); BARR;
    LOAD_A(0, 1);
    BARR; LGKM0; MFMA_Q(1, 1); BARR;
    LOAD_B(0, 0);
    BARR; LGKM0; MFMA_Q(1, 0); VMC(0); BARR;
    LOAD_A(1, 0); LOAD_B(1, 0);
    BARR; LGKM0; MFMA_Q(0, 0); BARR;
    LOAD_B(1, 1);
    BARR; LGKM0; MFMA_Q(0, 1); BARR;
    LOAD_A(1, 1);
    BARR; LGKM0; MFMA_Q(1, 1); BARR;
    LOAD_B(1, 0);
    BARR; LGKM0; MFMA_Q(1, 0);

    // -------- C write: C/D layout col=lane&15 (n), row=(lane>>4)*4+r (m) --------
    const int crow = (lane >> 4) * 4;
    const int ccol = lane & 15;
#pragma unroll
    for (int mh = 0; mh < 2; ++mh)
#pragma unroll
        for (int nh = 0; nh < 2; ++nh)
#pragma unroll
            for (int j = 0; j < 2; ++j) {
                const int n = n0 + nh * 128 + wn_l * 32 + j * 16 + ccol;
                const float bv = bias[n];
#pragma unroll
                for (int i = 0; i < 4; ++i) {
                    const int m = m0 + mh * 128 + wm_l * 64 + i * 16 + crow;
#pragma unroll
                    for (int r = 0; r < 4; ++r)
                        out[(size_t)(m + r) * OUTF + n] = acc[mh][i][nh][j][r] + bv;
                }
            }
}

// ---------------- fallback (ws too small): fused fp32 tiled GEMM ----------------
__global__ __launch_bounds__(256) void fused_fallback(const float* __restrict__ x,
                                                      const int* __restrict__ codes,
                                                      const float* __restrict__ absmax,
                                                      const float* __restrict__ codebook,
                                                      const float* __restrict__ bias,
                                                      float* __restrict__ out) {
    __shared__ float xs[64][17];
    __shared__ float wsm[64][17];
    __shared__ float cb[16];
    const int tid = threadIdx.x;
    if (tid < 16) cb[tid] = codebook[tid];
    const int m0 = blockIdx.y * 64, n0 = blockIdx.x * 64;
    float acc[4][4] = {};
    const int tr = tid >> 4, tc = tid & 15;
    for (int k0 = 0; k0 < INF; k0 += 16) {
        __syncthreads();
#pragma unroll
        for (int i = 0; i < 4; i++) {
            int e = i * 256 + tid;
            int r = e >> 4, c = e & 15;
            xs[r][c] = x[(size_t)(m0 + r) * INF + k0 + c];
            size_t widx = (size_t)(n0 + r) * INF + k0 + c;
            wsm[r][c] = cb[codes[widx]] * absmax[widx >> 6];
        }
        __syncthreads();
#pragma unroll
        for (int kk = 0; kk < 16; kk++) {
            float xv[4], wv[4];
#pragma unroll
            for (int i = 0; i < 4; i++) xv[i] = xs[tr * 4 + i][kk];
#pragma unroll
            for (int j = 0; j < 4; j++) wv[j] = wsm[tc * 4 + j][kk];
#pragma unroll
            for (int i = 0; i < 4; i++)
#pragma unroll
                for (int j = 0; j < 4; j++) acc[i][j] += xv[i] * wv[j];
        }
    }
#pragma unroll
    for (int i = 0; i < 4; i++)
#pragma unroll
        for (int j = 0; j < 4; j++) {
            int m = m0 + tr * 4 + i, n = n0 + tc * 4 + j;
            out[(size_t)m * OUTF + n] = acc[i][j] + bias[n];
        }
}

extern "C" void kernel_launch(void* const* d_in, const int* in_sizes, int n_in,
                              void* d_out, int out_size, void* d_ws, size_t ws_size,
                              hipStream_t stream) {
    const float* x        = (const float*)d_in[0];
    const int*   codes    = (const int*)d_in[1];
    const float* absmax   = (const float*)d_in[2];
    const float* codebook = (const float*)d_in[3];
    const float* bias     = (const float*)d_in[4];
    float* out = (float*)d_out;

    const size_t wbytes = (size_t)NCODES * 2;                 // 90.2 MB bf16 W
    const size_t xbytes = (size_t)TOKENS * INF * 2;           // 67.1 MB bf16 X

    if (ws_size >= wbytes + xbytes) {
        unsigned short* wq = (unsigned short*)d_ws;
        unsigned short* xq = (unsigned short*)((char*)d_ws + wbytes);
        dequant_w<<<NCODES / 2048, 256, 0, stream>>>(codes, absmax, codebook, wq);
        cast_x<<<(TOKENS * INF) / 2048, 256, 0, stream>>>(x, xq);
        gemm_bf16_8p<<<dim3((TOKENS / BM) * (OUTF / BN)), 512, 0, stream>>>(xq, wq, bias, out);
    } else {
        dim3 grid(OUTF / 64, TOKENS / 64);
        fused_fallback<<<grid, 256, 0, stream>>>(x, codes, absmax, codebook, bias, out);
    }
}

// Round 2
// 1248.158 us; speedup vs baseline: 1.1474x; 1.0028x over previous
//
#include <hip/hip_runtime.h>
#include <hip/hip_bf16.h>
#include <stdint.h>

#define TOKENS 8192
#define OUTF   11008
#define INF    4096
#define NCODES (45088768)   // OUTF * INF

typedef __bf16 bf16x8 __attribute__((ext_vector_type(8)));
typedef float  f32x4  __attribute__((ext_vector_type(4)));

__device__ __forceinline__ unsigned short f32_to_bf16_rne(float f) {
    union { float f; unsigned int u; } v; v.f = f;
    unsigned int u = v.u;
    unsigned int r = u + 0x7fffu + ((u >> 16) & 1u);
    return (unsigned short)(r >> 16);
}

// ---------------- dequant W: codes(int32) * codebook * absmax -> bf16 ----------------
__global__ __launch_bounds__(256) void dequant_w(const int* __restrict__ codes,
                                                 const float* __restrict__ absmax,
                                                 const float* __restrict__ codebook,
                                                 unsigned short* __restrict__ wq) {
    __shared__ float cb[16];
    if (threadIdx.x < 16) cb[threadIdx.x] = codebook[threadIdx.x];
    __syncthreads();
    size_t idx = ((size_t)blockIdx.x * 256 + threadIdx.x) * 8;   // grid sized exactly
    float am = absmax[idx >> 6];                                  // 8 | 64 -> one absmax per 8-chunk
    const int4* cp = (const int4*)(codes + idx);
    int4 c0 = cp[0];
    int4 c1 = cp[1];
    union { unsigned short s[8]; uint4 v; } u;
    u.s[0] = f32_to_bf16_rne(cb[c0.x] * am);
    u.s[1] = f32_to_bf16_rne(cb[c0.y] * am);
    u.s[2] = f32_to_bf16_rne(cb[c0.z] * am);
    u.s[3] = f32_to_bf16_rne(cb[c0.w] * am);
    u.s[4] = f32_to_bf16_rne(cb[c1.x] * am);
    u.s[5] = f32_to_bf16_rne(cb[c1.y] * am);
    u.s[6] = f32_to_bf16_rne(cb[c1.z] * am);
    u.s[7] = f32_to_bf16_rne(cb[c1.w] * am);
    *(uint4*)(wq + idx) = u.v;
}

// ---------------- cast x: fp32 -> bf16 ----------------
__global__ __launch_bounds__(256) void cast_x(const float* __restrict__ x,
                                              unsigned short* __restrict__ xq) {
    size_t idx = ((size_t)blockIdx.x * 256 + threadIdx.x) * 8;   // grid sized exactly
    float4 a = *(const float4*)(x + idx);
    float4 b = *(const float4*)(x + idx + 4);
    union { unsigned short s[8]; uint4 v; } u;
    u.s[0] = f32_to_bf16_rne(a.x);
    u.s[1] = f32_to_bf16_rne(a.y);
    u.s[2] = f32_to_bf16_rne(a.z);
    u.s[3] = f32_to_bf16_rne(a.w);
    u.s[4] = f32_to_bf16_rne(b.x);
    u.s[5] = f32_to_bf16_rne(b.y);
    u.s[6] = f32_to_bf16_rne(b.z);
    u.s[7] = f32_to_bf16_rne(b.w);
    *(uint4*)(xq + idx) = u.v;
}

// ======================= 256x256 8-phase bf16 MFMA GEMM (m201 template port) =======================
// C[M,N] = X[M,K] * W[N,K]^T + bias.  BM=BN=256, BK=64, 512 thr (2x4 waves), LDS 128KiB dbuf.
// R2: LDS-read-pipe diet. The binding resource is LDS read BW (24 ds_read_b128/K-tile/wave is
// the information-theoretic minimum: A 16KB + B 8KB per wave).  R1 issued 28 (B-half-0 reloaded
// in ph4 because b regs were clobbered).  Fix: persistent bA (loaded ph1, used ph1+ph4) and bB
// (loaded ph2, used ph2+ph3) -> ph4/ph8 are ds_read-free; 28->24 reads (-14% on binding pipe).
// Staging order/vmcnt/slot lifetimes unchanged from R1 (B0's last LDS read moves EARLIER).
// R2b: non-temporal C stores — the 400MB fp32 output stream was evicting the L3-resident
// W/X panels (FETCH 550MB vs 157MB working set), turning stage loads into ~900cy HBM misses
// that vmcnt(6)'s 3-phase prefetch depth can't cover.
#define BM 256
#define BN 256
#define BK 64

#define GLLDS(SRC, DST)                                                                   \
    __builtin_amdgcn_global_load_lds((const __attribute__((address_space(1))) void*)(SRC),\
                                     (__attribute__((address_space(3))) void*)(DST), 16, 0, 0)

#define STAGE_A(KT, HALF, BUF) do {                                                       \
    const unsigned short* _s = gA + (size_t)(HALF) * (128 * INF) + (size_t)(KT) * BK;     \
    GLLDS(_s,                   &lA[BUF][(HALF) * 8192 + tid * 8]);                       \
    GLLDS(_s + (size_t)64 * INF, &lA[BUF][(HALF) * 8192 + tid * 8 + 4096]); } while (0)

#define STAGE_B(KT, HALF, BUF) do {                                                       \
    const unsigned short* _s = gB + (size_t)(HALF) * (128 * INF) + (size_t)(KT) * BK;     \
    GLLDS(_s,                   &lB[BUF][(HALF) * 8192 + tid * 8]);                       \
    GLLDS(_s + (size_t)64 * INF, &lB[BUF][(HALF) * 8192 + tid * 8 + 4096]); } while (0)

#define LOAD_A(BUF, MH) do { _Pragma("unroll")                                            \
    for (int i = 0; i < 4; ++i) {                                                         \
        a[i][0] = *(const bf16x8*)&lA[BUF][(MH) * 8192 + i * 1024 + aRow + sw0];          \
        a[i][1] = *(const bf16x8*)&lA[BUF][(MH) * 8192 + i * 1024 + aRow + sw1]; } } while (0)

#define LOAD_BX(BUF, NH, DST) do { _Pragma("unroll")                                      \
    for (int j = 0; j < 2; ++j) {                                                         \
        DST[j][0] = *(const bf16x8*)&lB[BUF][(NH) * 8192 + j * 1024 + bRow + sw0];        \
        DST[j][1] = *(const bf16x8*)&lB[BUF][(NH) * 8192 + j * 1024 + bRow + sw1]; } } while (0)

#define MFMA_Q(MH, NH, BSRC) do {                                                         \
    __builtin_amdgcn_s_setprio(1);                                                        \
    _Pragma("unroll") for (int kc = 0; kc < 2; ++kc)                                      \
    _Pragma("unroll") for (int i = 0; i < 4; ++i)                                         \
    _Pragma("unroll") for (int j = 0; j < 2; ++j)                                         \
        acc[MH][i][NH][j] = __builtin_amdgcn_mfma_f32_16x16x32_bf16(                      \
            a[i][kc], BSRC[j][kc], acc[MH][i][NH][j], 0, 0, 0);                           \
    __builtin_amdgcn_s_setprio(0); } while (0)

#define BARR   __builtin_amdgcn_s_barrier()
#define LGKM0  asm volatile("s_waitcnt lgkmcnt(0)" ::: "memory")
#define VMC(N) asm volatile("s_waitcnt vmcnt(" #N ")" ::: "memory")

__global__ __launch_bounds__(512, 2) void gemm_bf16_8p(const unsigned short* __restrict__ Xb,  // [TOKENS][INF]
                                                       const unsigned short* __restrict__ Wb,  // [OUTF][INF]
                                                       const float* __restrict__ bias,
                                                       float* __restrict__ out) {
    __shared__ __align__(16) unsigned short lA[2][BM * BK];   // 2 x 32KB
    __shared__ __align__(16) unsigned short lB[2][BN * BK];   // 2 x 32KB

    // grid: 32 m-tiles x 43 n-tiles = 1376 = 8*172 -> bijective chunked XCD swizzle (T1).
    const int bid  = blockIdx.x;
    const int xcd  = bid & 7;
    const int loc  = bid >> 3;          // 0..171
    const int mt   = xcd * 4 + (loc & 3);
    const int nt   = loc >> 2;          // 0..42
    const int m0   = mt * BM;
    const int n0   = nt * BN;

    const int tid  = threadIdx.x;
    const int lane = tid & 63;
    const int wave = tid >> 6;          // 0..7
    const int wm_l = wave >> 2;         // 0..1
    const int wn_l = wave & 3;          // 0..3

    // fragment-read addressing (swizzled): row&7 == lane&7 for every frag row
    const int frow = lane & 15;
    const int klan = lane >> 4;                  // 0..3
    const int f7   = lane & 7;
    const int sw0  = ((klan)     ^ f7) * 8;      // kc=0 granule offset (elems)
    const int sw1  = ((klan + 4) ^ f7) * 8;      // kc=1
    const int aRow = (wm_l * 64 + frow) * BK;
    const int bRow = (wn_l * 32 + frow) * BK;

    // staging: chunk tid = (row rl, granule tid&7); source pre-swizzled by g^(rl&7)
    const int rl   = tid >> 3;                   // 0..63
    const int gsw  = (tid & 7) ^ (rl & 7);
    const unsigned short* gA = Xb + (size_t)(m0 + rl) * INF + gsw * 8;
    const unsigned short* gB = Wb + (size_t)(n0 + rl) * INF + gsw * 8;

    f32x4 acc[2][4][2][2];
#pragma unroll
    for (int mh = 0; mh < 2; ++mh)
#pragma unroll
        for (int i = 0; i < 4; ++i)
#pragma unroll
            for (int nh = 0; nh < 2; ++nh)
#pragma unroll
                for (int j = 0; j < 2; ++j)
#pragma unroll
                    for (int r = 0; r < 4; ++r) acc[mh][i][nh][j][r] = 0.0f;

    bf16x8 a[4][2], bA[2][2], bB[2][2];

    // -------- prologue: stage h0..h6 (Kt0 full + Kt1 A0,B1,A1), land Kt0 --------
    STAGE_A(0, 0, 0); STAGE_B(0, 1, 0); STAGE_A(0, 1, 0); STAGE_B(0, 0, 0);
    STAGE_A(1, 0, 1); STAGE_B(1, 1, 1); STAGE_A(1, 1, 1);
    VMC(6);
    BARR;

    // -------- main loop: 31 iters x 2 K-tiles; 8 phases/iter; 24 ds_read_b128/K-tile --------
    for (int it = 0; it < 31; ++it) {
        const int kt1 = 2 * it + 1, kt2 = 2 * it + 2, kt3 = 2 * it + 3;
        // ph1: q(0,0) of Kt(2it) in buf0 — A0 (8 reads) + B0 (4 reads, persists to ph4)
        LOAD_A(0, 0); LOAD_BX(0, 0, bA); STAGE_B(kt1, 0, 1);
        BARR; LGKM0; MFMA_Q(0, 0, bA); BARR;
        // ph2: q(0,1) — B1 (4 reads, persists to ph3)
        LOAD_BX(0, 1, bB); STAGE_A(kt2, 0, 0);
        BARR; LGKM0; MFMA_Q(0, 1, bB); BARR;
        // ph3: q(1,1) — A1 (8 reads)
        LOAD_A(0, 1); STAGE_B(kt2, 1, 0);
        BARR; LGKM0; MFMA_Q(1, 1, bB); BARR;
        // ph4: q(1,0) — ds_read-free (a from ph3, bA from ph1); counted drain -> Kt(2it+1) landed
        STAGE_A(kt2, 1, 0);
        BARR; LGKM0; MFMA_Q(1, 0, bA); VMC(6); BARR;
        // ph5: q(0,0) of Kt(2it+1) in buf1
        LOAD_A(1, 0); LOAD_BX(1, 0, bA); STAGE_B(kt2, 0, 0);
        BARR; LGKM0; MFMA_Q(0, 0, bA); BARR;
        // ph6: q(0,1)
        LOAD_BX(1, 1, bB); STAGE_A(kt3, 0, 1);
        BARR; LGKM0; MFMA_Q(0, 1, bB); BARR;
        // ph7: q(1,1)
        LOAD_A(1, 1); STAGE_B(kt3, 1, 1);
        BARR; LGKM0; MFMA_Q(1, 1, bB); BARR;
        // ph8: q(1,0) — ds_read-free; counted drain -> Kt(2it+2) landed
        STAGE_A(kt3, 1, 1);
        BARR; LGKM0; MFMA_Q(1, 0, bA); VMC(6); BARR;
    }

    // -------- epilogue: Kt62 (buf0) + Kt63 (buf1); stage only h255, drain once --------
    LOAD_A(0, 0); LOAD_BX(0, 0, bA); STAGE_B(63, 0, 1);
    BARR; LGKM0; MFMA_Q(0, 0, bA); BARR;
    LOAD_BX(0, 1, bB);
    BARR; LGKM0; MFMA_Q(0, 1, bB); BARR;
    LOAD_A(0, 1);
    BARR; LGKM0; MFMA_Q(1, 1, bB); BARR;
    BARR; LGKM0; MFMA_Q(1, 0, bA); VMC(0); BARR;
    LOAD_A(1, 0); LOAD_BX(1, 0, bA);
    BARR; LGKM0; MFMA_Q(0, 0, bA); BARR;
    LOAD_BX(1, 1, bB);
    BARR; LGKM0; MFMA_Q(0, 1, bB); BARR;
    LOAD_A(1, 1);
    BARR; LGKM0; MFMA_Q(1, 1, bB); BARR;
    LGKM0; MFMA_Q(1, 0, bA);

    // -------- C write: C/D layout col=lane&15 (n), row=(lane>>4)*4+r (m) --------
    // Non-temporal: keep the 400MB output stream from evicting L3-resident W/X panels.
    const int crow = (lane >> 4) * 4;
    const int ccol = lane & 15;
#pragma unroll
    for (int mh = 0; mh < 2; ++mh)
#pragma unroll
        for (int nh = 0; nh < 2; ++nh)
#pragma unroll
            for (int j = 0; j < 2; ++j) {
                const int n = n0 + nh * 128 + wn_l * 32 + j * 16 + ccol;
                const float bv = bias[n];
#pragma unroll
                for (int i = 0; i < 4; ++i) {
                    const int m = m0 + mh * 128 + wm_l * 64 + i * 16 + crow;
#pragma unroll
                    for (int r = 0; r < 4; ++r) {
                        const float v = acc[mh][i][nh][j][r] + bv;
                        __builtin_nontemporal_store(v, &out[(size_t)(m + r) * OUTF + n]);
                    }
                }
            }
}

// ---------------- fallback (ws too small): fused fp32 tiled GEMM ----------------
__global__ __launch_bounds__(256) void fused_fallback(const float* __restrict__ x,
                                                      const int* __restrict__ codes,
                                                      const float* __restrict__ absmax,
                                                      const float* __restrict__ codebook,
                                                      const float* __restrict__ bias,
                                                      float* __restrict__ out) {
    __shared__ float xs[64][17];
    __shared__ float wsm[64][17];
    __shared__ float cb[16];
    const int tid = threadIdx.x;
    if (tid < 16) cb[tid] = codebook[tid];
    const int m0 = blockIdx.y * 64, n0 = blockIdx.x * 64;
    float acc[4][4] = {};
    const int tr = tid >> 4, tc = tid & 15;
    for (int k0 = 0; k0 < INF; k0 += 16) {
        __syncthreads();
#pragma unroll
        for (int i = 0; i < 4; i++) {
            int e = i * 256 + tid;
            int r = e >> 4, c = e & 15;
            xs[r][c] = x[(size_t)(m0 + r) * INF + k0 + c];
            size_t widx = (size_t)(n0 + r) * INF + k0 + c;
            wsm[r][c] = cb[codes[widx]] * absmax[widx >> 6];
        }
        __syncthreads();
#pragma unroll
        for (int kk = 0; kk < 16; kk++) {
            float xv[4], wv[4];
#pragma unroll
            for (int i = 0; i < 4; i++) xv[i] = xs[tr * 4 + i][kk];
#pragma unroll
            for (int j = 0; j < 4; j++) wv[j] = wsm[tc * 4 + j][kk];
#pragma unroll
            for (int i = 0; i < 4; i++)
#pragma unroll
                for (int j = 0; j < 4; j++) acc[i][j] += xv[i] * wv[j];
        }
    }
#pragma unroll
    for (int i = 0; i < 4; i++)
#pragma unroll
        for (int j = 0; j < 4; j++) {
            int m = m0 + tr * 4 + i, n = n0 + tc * 4 + j;
            out[(size_t)m * OUTF + n] = acc[i][j] + bias[n];
        }
}

extern "C" void kernel_launch(void* const* d_in, const int* in_sizes, int n_in,
                              void* d_out, int out_size, void* d_ws, size_t ws_size,
                              hipStream_t stream) {
    const float* x        = (const float*)d_in[0];
    const int*   codes    = (const int*)d_in[1];
    const float* absmax   = (const float*)d_in[2];
    const float* codebook = (const float*)d_in[3];
    const float* bias     = (const float*)d_in[4];
    float* out = (float*)d_out;

    const size_t wbytes = (size_t)NCODES * 2;                 // 90.2 MB bf16 W
    const size_t xbytes = (size_t)TOKENS * INF * 2;           // 67.1 MB bf16 X

    if (ws_size >= wbytes + xbytes) {
        unsigned short* wq = (unsigned short*)d_ws;
        unsigned short* xq = (unsigned short*)((char*)d_ws + wbytes);
        dequant_w<<<NCODES / 2048, 256, 0, stream>>>(codes, absmax, codebook, wq);
        cast_x<<<(TOKENS * INF) / 2048, 256, 0, stream>>>(x, xq);
        gemm_bf16_8p<<<dim3((TOKENS / BM) * (OUTF / BN)), 512, 0, stream>>>(xq, wq, bias, out);
    } else {
        dim3 grid(OUTF / 64, TOKENS / 64);
        fused_fallback<<<grid, 64 * 4, 0, stream>>>(x, codes, absmax, codebook, bias, out);
    }
}